// Round 21
// baseline (45632.492 us; speedup 1.0000x reference)
//
#include <hip/hip_runtime.h>

// Echo-state network recurrence on MI355X (gfx950).
// Round-32: NO-SLEEP A/B. r31 (sc0) was null -> commit-flavor exhausted;
// plain store restored. The sleep(2) pre-poll delay entered in r13
// BUNDLED with pk-FMA and was never isolated. Evidence it may be pure
// overhead: r28 showed +128cyc sleep -> +225cyc/step (super-linear --
// sleep sits serially in the ring's fixed point); r26 measured poll
// ~690cyc = sleep + ~1 FAILED + 1 success round, i.e. the first round
// fails even WITH the sleep, so the sleep isn't absorbing the failed
// round -- detection is set by commit arrival, not poll start. Removing
// it saves up to 128cyc/step (~2.7ms) if so; costs ~+120cyc/step if the
// counter-hypothesis (sleep-protective) is right. Cheapest remaining
// decisive experiment; if null/worse, the serial chain is fully explored
// and r29/r30 is the floor. Everything else identical to r30: reader
// wave + treadmill, u software pipeline, cooperative quarter polling,
// plain-store publish, full 4-tag check, LDS placement force.
// Datapath untouched -> absmax 0.125.

#define HH    1024
#define TT    50000
#define WASH  200
#define NBROLE 32   // block role b owns rows [32b, 32b+32); wave ww rows [32b+8ww, +8)
#define NBLK  512
#define NT    320   // 4 compute waves + 1 reader wave
#define SPIN_CAP (1u << 20)
#define LDSPAD 98304   // 96 KiB total LDS -> 1 block/CU (LDS pool 160 KiB)

typedef unsigned int u32;
typedef u32 u32x4 __attribute__((ext_vector_type(4)));
typedef float f32x4 __attribute__((ext_vector_type(4)));
typedef float f32x2 __attribute__((ext_vector_type(2)));

__device__ __forceinline__ float fast_tanh(float x) {
  // tanh(x) = 1 - 2/(exp2(2x*log2e)+1); safe at +/-inf.
  float e = __builtin_amdgcn_exp2f(x * 2.8853900817779268f);
  return fmaf(-2.0f, __builtin_amdgcn_rcpf(e + 1.0f), 1.0f);
}

template <int CTRL>
__device__ __forceinline__ float dpp_movf(float x) {
  return __int_as_float(__builtin_amdgcn_update_dpp(
      0, __float_as_int(x), CTRL, 0xF, 0xF, true));
}
__device__ __forceinline__ float swz_xor16(float x) {
  return __int_as_float(__builtin_amdgcn_ds_swizzle(__float_as_int(x), 0x401F));
}

#define YREDUCE()                                                         \
  { y += __shfl_xor(y, 32);                                               \
    y += swz_xor16(y);                                                    \
    y += dpp_movf<0x128>(y);   /* row_ror:8   */                          \
    y += dpp_movf<0x141>(y);   /* half mirror */                          \
    y += dpp_movf<0x1B>(y);    /* quad reverse*/                          \
    y += dpp_movf<0xB1>(y); }  /* quad xor1   */

// single 16B poll load: own quarter only (lane l -> cols 256*ww + 4l .. +3)
#define POLL_ISSUE1(bp)                                                   \
  asm volatile("global_load_dwordx4 %0, %1, off sc1" : "=v"(p) : "v"(bp))
#define POLL_WAIT1()                                                      \
  asm volatile("s_waitcnt vmcnt(0)" : "+v"(p))

// reader: 4 batched 16B loads cover all 1024 packed elements
#define RISSUE(bp)                                                                    \
  asm volatile("global_load_dwordx4 %0, %1, off sc1"             : "=v"(p0) : "v"(bp)); \
  asm volatile("global_load_dwordx4 %0, %1, off offset:1024 sc1" : "=v"(p1) : "v"(bp)); \
  asm volatile("global_load_dwordx4 %0, %1, off offset:2048 sc1" : "=v"(p2) : "v"(bp)); \
  asm volatile("global_load_dwordx4 %0, %1, off offset:3072 sc1" : "=v"(p3) : "v"(bp))
#define RWAIT()                                                           \
  asm volatile("s_waitcnt vmcnt(0)"                                       \
               : "+v"(p0), "+v"(p1), "+v"(p2), "+v"(p3))

// FULL 4-dword tag check -- load-bearing (partial-commit visibility of
// coalesced wave stores means every dword's tag matters).
#define TAGBAD(q) ((((q.x ^ want) | (q.y ^ want) | (q.z ^ want) | (q.w ^ want)) & 0xFFu))

// unpack one 16B chunk into two f32x2 value pairs (pair b2, b2+1)
#define UNPACK2(q, b2)                                                    \
  { xv2[b2+0] = (f32x2){__uint_as_float(q.x & 0xFFFFFF00u),               \
                        __uint_as_float(q.y & 0xFFFFFF00u)};              \
    xv2[b2+1] = (f32x2){__uint_as_float(q.z & 0xFFFFFF00u),               \
                        __uint_as_float(q.w & 0xFFFFFF00u)}; }

// --- named weight registers: row r, pairs 0..7 (cols 256*(p>>1)+4l+{2(p&1),+1})
#define DECLW(r) f32x2 W##r##0, W##r##1, W##r##2, W##r##3,                \
                      W##r##4, W##r##5, W##r##6, W##r##7

#define LOADW(r) do {                                                     \
  const float* wp = w_res + (size_t)(32 * b + 8 * ww + r) * HH + 4 * l;   \
  f32x4 va = *(const f32x4*)(wp);                                         \
  f32x4 vb = *(const f32x4*)(wp + 256);                                   \
  f32x4 vc = *(const f32x4*)(wp + 512);                                   \
  f32x4 vd = *(const f32x4*)(wp + 768);                                   \
  W##r##0 = (f32x2){va.x, va.y}; W##r##1 = (f32x2){va.z, va.w};           \
  W##r##2 = (f32x2){vb.x, vb.y}; W##r##3 = (f32x2){vb.z, vb.w};           \
  W##r##4 = (f32x2){vc.x, vc.y}; W##r##5 = (f32x2){vc.z, vc.w};           \
  W##r##6 = (f32x2){vd.x, vd.y}; W##r##7 = (f32x2){vd.z, vd.w};           \
} while (0)

// jj ascending per accumulator -> identical summation order to r13-r31
#define FMAR(r) do {                                                      \
  acc2[r] = __builtin_elementwise_fma(W##r##0, xv2[0], acc2[r]);          \
  acc2[r] = __builtin_elementwise_fma(W##r##1, xv2[1], acc2[r]);          \
  acc2[r] = __builtin_elementwise_fma(W##r##2, xv2[2], acc2[r]);          \
  acc2[r] = __builtin_elementwise_fma(W##r##3, xv2[3], acc2[r]);          \
  acc2[r] = __builtin_elementwise_fma(W##r##4, xv2[4], acc2[r]);          \
  acc2[r] = __builtin_elementwise_fma(W##r##5, xv2[5], acc2[r]);          \
  acc2[r] = __builtin_elementwise_fma(W##r##6, xv2[6], acc2[r]);          \
  acc2[r] = __builtin_elementwise_fma(W##r##7, xv2[7], acc2[r]);          \
} while (0)

__global__ __launch_bounds__(NT, 1) void esn_kernel(
    const float* __restrict__ u,
    const float* __restrict__ w_in,
    const float* __restrict__ w_res,
    const float* __restrict__ w_out,
    const int*   __restrict__ mask,
    float*       __restrict__ out,
    char*        __restrict__ ws)
{
  const int tid = threadIdx.x;
  const int l  = tid & 63;     // lane within wave
  const int ww = tid >> 6;     // wave id within block (0..4); 4 = reader

  // --- team formation: XCD 0 only, first 32 claimant BLOCKS persist ---
  u32 xcc;
  asm("s_getreg_b32 %0, hwreg(HW_REG_XCC_ID)" : "=s"(xcc));
  if (xcc != 0) return;        // uniform per block (block lives on one CU)

  // PLACEMENT FORCE (r22-proven): 96 KiB static LDS -> 1 block/CU ->
  // the 32 claim winners sit on 32 distinct CUs.
  __shared__ __align__(16) char lds_all[LDSPAD];
  float* lds_c = (float*)lds_all;                        // 4 KB coeffs
  u32 (*lds_x)[HH] = (u32 (*)[HH])(lds_all + 4096);      // 2x4 KB state
  int* slot_p = (int*)(lds_all + 4096 + 8192);

  if (tid == 0) *slot_p = atomicAdd((int*)ws, 1);  // ws[0..63] zeroed each launch
  // init readout coeffs while the claim settles
  for (int h = tid; h < HH; h += NT) lds_c[mask[h]] = w_out[h];
  __syncthreads();
  const int b = *slot_p;
  if (b >= NBROLE) return;

  u32* xb0 = (u32*)(ws + 4096);        // parity-0 packed buffer (4 KB)
  u32* xb1 = xb0 + HH;                 // parity-1 packed buffer (4 KB)

  // ================= READER WAVE (ww == 4) =================
  if (ww == 4) {
    if (b != 0) {
      // barrier treadmill: keep this block's per-workgroup barrier count
      // aligned with its 4 compute waves (TT-1 barriers), zero work.
      for (int t = 1; t < TT; ++t) __syncthreads();
      return;
    }
    // active reader: computes EVERY output, off the compute critical path
    f32x2 cr2[8];
#pragma unroll
    for (int k = 0; k < 4; ++k) {
      f32x4 v = *(const f32x4*)(lds_c + 256 * k + 4 * l);
      cr2[2*k+0] = (f32x2){v.x, v.y};
      cr2[2*k+1] = (f32x2){v.z, v.w};
    }
    const u32* rA0 = xb0 + 4 * l;
    const u32* rA1 = xb1 + 4 * l;
    u32x4 p0, p1, p2, p3;
    int dead = 0;
    for (int t = 1; t < TT; ++t) {
      const bool work = (t - 1 >= WASH) && !dead;
      if (work) {
        // poll full state x_{t-1} (tag t) -- concurrent with the compute
        // waves' quarter polls; no artificial delay (r32 A/B).
        const u32* src = ((t - 1) & 1) ? rA1 : rA0;
        const u32 want = (u32)t & 0xFFu;
        u32 guard = 0;
        for (;;) {
          RISSUE(src);
          RWAIT();
          if (!(TAGBAD(p0) | TAGBAD(p1) | TAGBAD(p2) | TAGBAD(p3))) break;
          if (++guard > SPIN_CAP) { dead = 1; break; }
        }
      }
      __syncthreads();                 // cadence: one barrier per t, 1..TT-1
      if (work) {
        // y compute hidden under compute waves' LDS-read+FMA+fold phase
        f32x2 xv2[8];
        UNPACK2(p0, 0); UNPACK2(p1, 2); UNPACK2(p2, 4); UNPACK2(p3, 6);
        f32x2 y2 = (f32x2){0.f, 0.f};
#pragma unroll
        for (int jj = 0; jj < 8; ++jj)
          y2 = __builtin_elementwise_fma(cr2[jj], xv2[jj], y2);
        float y = y2.x + y2.y;
        YREDUCE();
        if (l == 0) out[t - 1 - WASH] = y;
      }
    }
    // final output: x_{TT-1} (tag TT) in buf[(TT-1)&1] = buf[1]
    if (!dead) {
      const u32 want = (u32)TT & 0xFFu;
      u32 guard = 0;
      for (;;) {
        RISSUE(rA1);
        RWAIT();
        if (!(TAGBAD(p0) | TAGBAD(p1) | TAGBAD(p2) | TAGBAD(p3))) break;
        if (++guard > SPIN_CAP) break;
      }
      f32x2 xv2[8];
      UNPACK2(p0, 0); UNPACK2(p1, 2); UNPACK2(p2, 4); UNPACK2(p3, 6);
      f32x2 y2 = (f32x2){0.f, 0.f};
#pragma unroll
      for (int jj = 0; jj < 8; ++jj)
        y2 = __builtin_elementwise_fma(cr2[jj], xv2[jj], y2);
      float y = y2.x + y2.y;
      YREDUCE();
      if (l == 0) out[TT - 1 - WASH] = y;
    }
    return;
  }

  // ================= COMPUTE WAVES (ww < 4) =================
  // weights: 8 rows x 8 col-pairs per lane (rows 32b+8ww .. +8)
  DECLW(0); DECLW(1); DECLW(2); DECLW(3);
  DECLW(4); DECLW(5); DECLW(6); DECLW(7);
  LOADW(0); LOADW(1); LOADW(2); LOADW(3);
  LOADW(4); LOADW(5); LOADW(6); LOADW(7);

  const float win = w_in[32 * b + 8 * ww + (l >> 3)];

  // own-quarter poll pointers: wave ww covers cols [256ww, 256ww+256)
  const u32* pS0 = xb0 + 256 * ww + 4 * l;
  const u32* pS1 = xb1 + 256 * ww + 4 * l;
  // publish pointers: lane (l&7)==0 stores row 32b+8ww+(l>>3)
  const int drow = 32 * b + 8 * ww + (l >> 3);
  u32* d0 = xb0 + drow;
  u32* d1 = xb1 + drow;
  // LDS staging address (own quarter)
  const int stg = 256 * ww + 4 * l;

  u32x4 p;
  const int lb32 = l & 32, lb16 = l & 16, lb8 = l & 8;
  int dead = 0;

  // U SOFTWARE PIPELINE (r30): u_cur consumed this step, reloaded
  // post-barrier -- outside the poll's vmcnt(0) window.
  float u_cur = u[0];

  for (int t = 0; t < TT; ++t) {
    const int pa = t & 1;
    const float u_t = u_cur;           // register, no load on poll path
    f32x2 acc2[8];
#pragma unroll
    for (int i = 0; i < 8; ++i) acc2[i] = (f32x2){0.f, 0.f};
    f32x2 xv2[8];

    if (t > 0) {
      const int h = pa ^ 1;            // source parity = (t-1)&1
      if (!dead) {
        // NO pre-poll sleep (r32 A/B): poll immediately; detection is
        // set by commit arrival. If this is worse, sleep(2) was
        // protective (absorbing a failed round) -> revert.
        const u32* src = h ? pS1 : pS0;
        const u32 want = (u32)t & 0xFFu;   // generation of x_{t-1}
        u32 guard = 0;
        for (;;) {
          POLL_ISSUE1(src);
          POLL_WAIT1();
          if (!TAGBAD(p)) break;
          if (++guard > SPIN_CAP) { dead = 1; break; }
        }
      }
      // stage own quarter to LDS; barrier; read full state from LDS
      *(u32x4*)(&lds_x[h][stg]) = p;
      __syncthreads();
      // reload u for the NEXT step, post-barrier (see pipeline note)
      u_cur = u[(t + 1 < TT) ? t + 1 : TT - 1];
      u32x4 c0 = *(const u32x4*)(&lds_x[h][  0 + 4 * l]);
      u32x4 c1 = *(const u32x4*)(&lds_x[h][256 + 4 * l]);
      u32x4 c2 = *(const u32x4*)(&lds_x[h][512 + 4 * l]);
      u32x4 c3 = *(const u32x4*)(&lds_x[h][768 + 4 * l]);
      UNPACK2(c0, 0); UNPACK2(c1, 2); UNPACK2(c2, 4); UNPACK2(c3, 6);
      // packed dual-pipe FP32: 64 v_pk_fma_f32
      FMAR(0); FMAR(1); FMAR(2); FMAR(3);
      FMAR(4); FMAR(5); FMAR(6); FMAR(7);
    } else {
      u_cur = u[1];                    // prologue: next step's input
    }

    // horizontal pair-sum, then fold 64 lanes x 8 accs -> row (l>>3) sum
    // on lanes with (l&7)==0
    const float a0 = acc2[0].x + acc2[0].y, a1 = acc2[1].x + acc2[1].y;
    const float a2 = acc2[2].x + acc2[2].y, a3 = acc2[3].x + acc2[3].y;
    const float a4 = acc2[4].x + acc2[4].y, a5 = acc2[5].x + acc2[5].y;
    const float a6 = acc2[6].x + acc2[6].y, a7 = acc2[7].x + acc2[7].y;
    float t0 = (lb32 ? a4 : a0) + __shfl_xor(lb32 ? a0 : a4, 32);
    float t1 = (lb32 ? a5 : a1) + __shfl_xor(lb32 ? a1 : a5, 32);
    float t2 = (lb32 ? a6 : a2) + __shfl_xor(lb32 ? a2 : a6, 32);
    float t3 = (lb32 ? a7 : a3) + __shfl_xor(lb32 ? a3 : a7, 32);
    float s0 = (lb16 ? t2 : t0) + swz_xor16(lb16 ? t0 : t2);
    float s1 = (lb16 ? t3 : t1) + swz_xor16(lb16 ? t1 : t3);
    float r0 = (lb8 ? s1 : s0) + dpp_movf<0x128>(lb8 ? s0 : s1);
    r0 += dpp_movf<0x141>(r0);
    r0 += dpp_movf<0x1B>(r0);
    r0 += dpp_movf<0xB1>(r0);

    float x_new = fast_tanh(fmaf(win, u_t, r0));
    // pack: RN-round mantissa to 15 bits, fuse generation tag (t+1)&0xFF
    u32 packed = ((__float_as_uint(x_new) + 0x80u) & 0xFFFFFF00u)
               | ((u32)(t + 1) & 0xFFu);
    if ((l & 7) == 0) {
      u32* dst = pa ? d1 : d0;          // x_t -> buf[t&1]
      // PLAIN store: write-through L1 -> dirty in XCD0's shared L2
      // (r9-proven; r16 atomics and r31 sc0 both failed to beat it).
      asm volatile("global_store_dword %0, %1, off" :: "v"(dst), "v"(packed));
    }
  }
}

extern "C" void kernel_launch(void* const* d_in, const int* in_sizes, int n_in,
                              void* d_out, int out_size, void* d_ws, size_t ws_size,
                              hipStream_t stream) {
  const float* u     = (const float*)d_in[0];
  const float* w_in  = (const float*)d_in[1];
  const float* w_res = (const float*)d_in[2];
  const float* w_out = (const float*)d_in[3];
  const int*   mask  = (const int*)d_in[4];
  float* out = (float*)d_out;

  // zero the block-claim counter; packed buffers rely on 0xAA poison
  // (tag byte 0xAA only ever compared against want in {1,2})
  hipMemsetAsync(d_ws, 0, 64, stream);

  esn_kernel<<<NBLK, NT, 0, stream>>>(u, w_in, w_res, w_out, mask, out,
                                      (char*)d_ws);
}

// Round 22
// 41826.202 us; speedup vs baseline: 1.0910x; 1.0910x over previous
//
#include <hip/hip_runtime.h>

// Echo-state network recurrence on MI355X (gfx950).
// Round-33: RESTORE BEST (r29/r30 config). r32 confirmed sleep(2) is
// protective: no-sleep = +3.8ms (+182cyc/step ~= one L2 RTT, the
// guaranteed-failed first round returning). Sleep landscape is a sharp V:
// 0 -> +3.8ms, 2 -> best, 4 -> +4.8ms; commit lands just inside the
// 128cyc window. FULL LEDGER now closed: compute (r13/14/30 null),
// poll BW (r15/25 soft), publish flavor (r16 atomic/r31 sc0 worse/null),
// poll quantization (r17/24 null), exchange structure (r23/25/27 barrier
// wins), first-poll timing (sleep2 optimal), placement (r22 -12% REAL),
// readout straggle (r29 -0.6% REAL). Period ~2008cyc = commit(~400) +
// RTT(~250) + sleep(128) + stage/barrier/ds_read(~270) + compute(~650) +
// E[max jitter](~300) -- a latency-bound fixed point; ten consecutive
// structural nulls say the pattern is exhausted. This round restores the
// best-measured kernel: reader wave + treadmill, sleep(2), cooperative
// quarter polling, plain-store publish, full 4-tag check, u software
// pipeline, LDS placement force. 41.84ms expected.

#define HH    1024
#define TT    50000
#define WASH  200
#define NBROLE 32   // block role b owns rows [32b, 32b+32); wave ww rows [32b+8ww, +8)
#define NBLK  512
#define NT    320   // 4 compute waves + 1 reader wave
#define SPIN_CAP (1u << 20)
#define LDSPAD 98304   // 96 KiB total LDS -> 1 block/CU (LDS pool 160 KiB)

typedef unsigned int u32;
typedef u32 u32x4 __attribute__((ext_vector_type(4)));
typedef float f32x4 __attribute__((ext_vector_type(4)));
typedef float f32x2 __attribute__((ext_vector_type(2)));

__device__ __forceinline__ float fast_tanh(float x) {
  // tanh(x) = 1 - 2/(exp2(2x*log2e)+1); safe at +/-inf.
  float e = __builtin_amdgcn_exp2f(x * 2.8853900817779268f);
  return fmaf(-2.0f, __builtin_amdgcn_rcpf(e + 1.0f), 1.0f);
}

template <int CTRL>
__device__ __forceinline__ float dpp_movf(float x) {
  return __int_as_float(__builtin_amdgcn_update_dpp(
      0, __float_as_int(x), CTRL, 0xF, 0xF, true));
}
__device__ __forceinline__ float swz_xor16(float x) {
  return __int_as_float(__builtin_amdgcn_ds_swizzle(__float_as_int(x), 0x401F));
}

#define YREDUCE()                                                         \
  { y += __shfl_xor(y, 32);                                               \
    y += swz_xor16(y);                                                    \
    y += dpp_movf<0x128>(y);   /* row_ror:8   */                          \
    y += dpp_movf<0x141>(y);   /* half mirror */                          \
    y += dpp_movf<0x1B>(y);    /* quad reverse*/                          \
    y += dpp_movf<0xB1>(y); }  /* quad xor1   */

// single 16B poll load: own quarter only (lane l -> cols 256*ww + 4l .. +3)
#define POLL_ISSUE1(bp)                                                   \
  asm volatile("global_load_dwordx4 %0, %1, off sc1" : "=v"(p) : "v"(bp))
#define POLL_WAIT1()                                                      \
  asm volatile("s_waitcnt vmcnt(0)" : "+v"(p))

// reader: 4 batched 16B loads cover all 1024 packed elements
#define RISSUE(bp)                                                                    \
  asm volatile("global_load_dwordx4 %0, %1, off sc1"             : "=v"(p0) : "v"(bp)); \
  asm volatile("global_load_dwordx4 %0, %1, off offset:1024 sc1" : "=v"(p1) : "v"(bp)); \
  asm volatile("global_load_dwordx4 %0, %1, off offset:2048 sc1" : "=v"(p2) : "v"(bp)); \
  asm volatile("global_load_dwordx4 %0, %1, off offset:3072 sc1" : "=v"(p3) : "v"(bp))
#define RWAIT()                                                           \
  asm volatile("s_waitcnt vmcnt(0)"                                       \
               : "+v"(p0), "+v"(p1), "+v"(p2), "+v"(p3))

// FULL 4-dword tag check -- load-bearing (partial-commit visibility of
// coalesced wave stores means every dword's tag matters).
#define TAGBAD(q) ((((q.x ^ want) | (q.y ^ want) | (q.z ^ want) | (q.w ^ want)) & 0xFFu))

// unpack one 16B chunk into two f32x2 value pairs (pair b2, b2+1)
#define UNPACK2(q, b2)                                                    \
  { xv2[b2+0] = (f32x2){__uint_as_float(q.x & 0xFFFFFF00u),               \
                        __uint_as_float(q.y & 0xFFFFFF00u)};              \
    xv2[b2+1] = (f32x2){__uint_as_float(q.z & 0xFFFFFF00u),               \
                        __uint_as_float(q.w & 0xFFFFFF00u)}; }

// --- named weight registers: row r, pairs 0..7 (cols 256*(p>>1)+4l+{2(p&1),+1})
#define DECLW(r) f32x2 W##r##0, W##r##1, W##r##2, W##r##3,                \
                      W##r##4, W##r##5, W##r##6, W##r##7

#define LOADW(r) do {                                                     \
  const float* wp = w_res + (size_t)(32 * b + 8 * ww + r) * HH + 4 * l;   \
  f32x4 va = *(const f32x4*)(wp);                                         \
  f32x4 vb = *(const f32x4*)(wp + 256);                                   \
  f32x4 vc = *(const f32x4*)(wp + 512);                                   \
  f32x4 vd = *(const f32x4*)(wp + 768);                                   \
  W##r##0 = (f32x2){va.x, va.y}; W##r##1 = (f32x2){va.z, va.w};           \
  W##r##2 = (f32x2){vb.x, vb.y}; W##r##3 = (f32x2){vb.z, vb.w};           \
  W##r##4 = (f32x2){vc.x, vc.y}; W##r##5 = (f32x2){vc.z, vc.w};           \
  W##r##6 = (f32x2){vd.x, vd.y}; W##r##7 = (f32x2){vd.z, vd.w};           \
} while (0)

// jj ascending per accumulator -> identical summation order to r13-r32
#define FMAR(r) do {                                                      \
  acc2[r] = __builtin_elementwise_fma(W##r##0, xv2[0], acc2[r]);          \
  acc2[r] = __builtin_elementwise_fma(W##r##1, xv2[1], acc2[r]);          \
  acc2[r] = __builtin_elementwise_fma(W##r##2, xv2[2], acc2[r]);          \
  acc2[r] = __builtin_elementwise_fma(W##r##3, xv2[3], acc2[r]);          \
  acc2[r] = __builtin_elementwise_fma(W##r##4, xv2[4], acc2[r]);          \
  acc2[r] = __builtin_elementwise_fma(W##r##5, xv2[5], acc2[r]);          \
  acc2[r] = __builtin_elementwise_fma(W##r##6, xv2[6], acc2[r]);          \
  acc2[r] = __builtin_elementwise_fma(W##r##7, xv2[7], acc2[r]);          \
} while (0)

__global__ __launch_bounds__(NT, 1) void esn_kernel(
    const float* __restrict__ u,
    const float* __restrict__ w_in,
    const float* __restrict__ w_res,
    const float* __restrict__ w_out,
    const int*   __restrict__ mask,
    float*       __restrict__ out,
    char*        __restrict__ ws)
{
  const int tid = threadIdx.x;
  const int l  = tid & 63;     // lane within wave
  const int ww = tid >> 6;     // wave id within block (0..4); 4 = reader

  // --- team formation: XCD 0 only, first 32 claimant BLOCKS persist ---
  u32 xcc;
  asm("s_getreg_b32 %0, hwreg(HW_REG_XCC_ID)" : "=s"(xcc));
  if (xcc != 0) return;        // uniform per block (block lives on one CU)

  // PLACEMENT FORCE (r22-proven): 96 KiB static LDS -> 1 block/CU ->
  // the 32 claim winners sit on 32 distinct CUs.
  __shared__ __align__(16) char lds_all[LDSPAD];
  float* lds_c = (float*)lds_all;                        // 4 KB coeffs
  u32 (*lds_x)[HH] = (u32 (*)[HH])(lds_all + 4096);      // 2x4 KB state
  int* slot_p = (int*)(lds_all + 4096 + 8192);

  if (tid == 0) *slot_p = atomicAdd((int*)ws, 1);  // ws[0..63] zeroed each launch
  // init readout coeffs while the claim settles
  for (int h = tid; h < HH; h += NT) lds_c[mask[h]] = w_out[h];
  __syncthreads();
  const int b = *slot_p;
  if (b >= NBROLE) return;

  u32* xb0 = (u32*)(ws + 4096);        // parity-0 packed buffer (4 KB)
  u32* xb1 = xb0 + HH;                 // parity-1 packed buffer (4 KB)

  // ================= READER WAVE (ww == 4) =================
  if (ww == 4) {
    if (b != 0) {
      // barrier treadmill: keep this block's per-workgroup barrier count
      // aligned with its 4 compute waves (TT-1 barriers), zero work.
      for (int t = 1; t < TT; ++t) __syncthreads();
      return;
    }
    // active reader: computes EVERY output, off the compute critical path
    f32x2 cr2[8];
#pragma unroll
    for (int k = 0; k < 4; ++k) {
      f32x4 v = *(const f32x4*)(lds_c + 256 * k + 4 * l);
      cr2[2*k+0] = (f32x2){v.x, v.y};
      cr2[2*k+1] = (f32x2){v.z, v.w};
    }
    const u32* rA0 = xb0 + 4 * l;
    const u32* rA1 = xb1 + 4 * l;
    u32x4 p0, p1, p2, p3;
    int dead = 0;
    for (int t = 1; t < TT; ++t) {
      const bool work = (t - 1 >= WASH) && !dead;
      if (work) {
        // poll full state x_{t-1} (tag t) -- concurrent with the compute
        // waves' quarter polls; the barrier waits for the global max
        // either way, so this adds no latency.
        __builtin_amdgcn_s_sleep(2);
        const u32* src = ((t - 1) & 1) ? rA1 : rA0;
        const u32 want = (u32)t & 0xFFu;
        u32 guard = 0;
        for (;;) {
          RISSUE(src);
          RWAIT();
          if (!(TAGBAD(p0) | TAGBAD(p1) | TAGBAD(p2) | TAGBAD(p3))) break;
          if (++guard > SPIN_CAP) { dead = 1; break; }
        }
      }
      __syncthreads();                 // cadence: one barrier per t, 1..TT-1
      if (work) {
        // y compute hidden under compute waves' LDS-read+FMA+fold phase
        f32x2 xv2[8];
        UNPACK2(p0, 0); UNPACK2(p1, 2); UNPACK2(p2, 4); UNPACK2(p3, 6);
        f32x2 y2 = (f32x2){0.f, 0.f};
#pragma unroll
        for (int jj = 0; jj < 8; ++jj)
          y2 = __builtin_elementwise_fma(cr2[jj], xv2[jj], y2);
        float y = y2.x + y2.y;
        YREDUCE();
        if (l == 0) out[t - 1 - WASH] = y;
      }
    }
    // final output: x_{TT-1} (tag TT) in buf[(TT-1)&1] = buf[1]
    if (!dead) {
      const u32 want = (u32)TT & 0xFFu;
      u32 guard = 0;
      for (;;) {
        RISSUE(rA1);
        RWAIT();
        if (!(TAGBAD(p0) | TAGBAD(p1) | TAGBAD(p2) | TAGBAD(p3))) break;
        if (++guard > SPIN_CAP) break;
      }
      f32x2 xv2[8];
      UNPACK2(p0, 0); UNPACK2(p1, 2); UNPACK2(p2, 4); UNPACK2(p3, 6);
      f32x2 y2 = (f32x2){0.f, 0.f};
#pragma unroll
      for (int jj = 0; jj < 8; ++jj)
        y2 = __builtin_elementwise_fma(cr2[jj], xv2[jj], y2);
      float y = y2.x + y2.y;
      YREDUCE();
      if (l == 0) out[TT - 1 - WASH] = y;
    }
    return;
  }

  // ================= COMPUTE WAVES (ww < 4) =================
  // weights: 8 rows x 8 col-pairs per lane (rows 32b+8ww .. +8)
  DECLW(0); DECLW(1); DECLW(2); DECLW(3);
  DECLW(4); DECLW(5); DECLW(6); DECLW(7);
  LOADW(0); LOADW(1); LOADW(2); LOADW(3);
  LOADW(4); LOADW(5); LOADW(6); LOADW(7);

  const float win = w_in[32 * b + 8 * ww + (l >> 3)];

  // own-quarter poll pointers: wave ww covers cols [256ww, 256ww+256)
  const u32* pS0 = xb0 + 256 * ww + 4 * l;
  const u32* pS1 = xb1 + 256 * ww + 4 * l;
  // publish pointers: lane (l&7)==0 stores row 32b+8ww+(l>>3)
  const int drow = 32 * b + 8 * ww + (l >> 3);
  u32* d0 = xb0 + drow;
  u32* d1 = xb1 + drow;
  // LDS staging address (own quarter)
  const int stg = 256 * ww + 4 * l;

  u32x4 p;
  const int lb32 = l & 32, lb16 = l & 16, lb8 = l & 8;
  int dead = 0;

  // U SOFTWARE PIPELINE (r30): u_cur consumed this step, reloaded
  // post-barrier -- outside the poll's vmcnt(0) window.
  float u_cur = u[0];

  for (int t = 0; t < TT; ++t) {
    const int pa = t & 1;
    const float u_t = u_cur;           // register, no load on poll path
    f32x2 acc2[8];
#pragma unroll
    for (int i = 0; i < 8; ++i) acc2[i] = (f32x2){0.f, 0.f};
    f32x2 xv2[8];

    if (t > 0) {
      const int h = pa ^ 1;            // source parity = (t-1)&1
      if (!dead) {
        // delayed first poll: sleep(2)=128cyc -- confirmed optimal
        // (r32: sleep0 +3.8ms; r28: sleep4 +4.8ms; sharp V minimum).
        __builtin_amdgcn_s_sleep(2);
        const u32* src = h ? pS1 : pS0;
        const u32 want = (u32)t & 0xFFu;   // generation of x_{t-1}
        u32 guard = 0;
        for (;;) {
          POLL_ISSUE1(src);
          POLL_WAIT1();
          if (!TAGBAD(p)) break;
          if (++guard > SPIN_CAP) { dead = 1; break; }
        }
      }
      // stage own quarter to LDS; barrier; read full state from LDS
      *(u32x4*)(&lds_x[h][stg]) = p;
      __syncthreads();
      // reload u for the NEXT step, post-barrier (see pipeline note)
      u_cur = u[(t + 1 < TT) ? t + 1 : TT - 1];
      u32x4 c0 = *(const u32x4*)(&lds_x[h][  0 + 4 * l]);
      u32x4 c1 = *(const u32x4*)(&lds_x[h][256 + 4 * l]);
      u32x4 c2 = *(const u32x4*)(&lds_x[h][512 + 4 * l]);
      u32x4 c3 = *(const u32x4*)(&lds_x[h][768 + 4 * l]);
      UNPACK2(c0, 0); UNPACK2(c1, 2); UNPACK2(c2, 4); UNPACK2(c3, 6);
      // packed dual-pipe FP32: 64 v_pk_fma_f32
      FMAR(0); FMAR(1); FMAR(2); FMAR(3);
      FMAR(4); FMAR(5); FMAR(6); FMAR(7);
    } else {
      u_cur = u[1];                    // prologue: next step's input
    }

    // horizontal pair-sum, then fold 64 lanes x 8 accs -> row (l>>3) sum
    // on lanes with (l&7)==0
    const float a0 = acc2[0].x + acc2[0].y, a1 = acc2[1].x + acc2[1].y;
    const float a2 = acc2[2].x + acc2[2].y, a3 = acc2[3].x + acc2[3].y;
    const float a4 = acc2[4].x + acc2[4].y, a5 = acc2[5].x + acc2[5].y;
    const float a6 = acc2[6].x + acc2[6].y, a7 = acc2[7].x + acc2[7].y;
    float t0 = (lb32 ? a4 : a0) + __shfl_xor(lb32 ? a0 : a4, 32);
    float t1 = (lb32 ? a5 : a1) + __shfl_xor(lb32 ? a1 : a5, 32);
    float t2 = (lb32 ? a6 : a2) + __shfl_xor(lb32 ? a2 : a6, 32);
    float t3 = (lb32 ? a7 : a3) + __shfl_xor(lb32 ? a3 : a7, 32);
    float s0 = (lb16 ? t2 : t0) + swz_xor16(lb16 ? t0 : t2);
    float s1 = (lb16 ? t3 : t1) + swz_xor16(lb16 ? t1 : t3);
    float r0 = (lb8 ? s1 : s0) + dpp_movf<0x128>(lb8 ? s0 : s1);
    r0 += dpp_movf<0x141>(r0);
    r0 += dpp_movf<0x1B>(r0);
    r0 += dpp_movf<0xB1>(r0);

    float x_new = fast_tanh(fmaf(win, u_t, r0));
    // pack: RN-round mantissa to 15 bits, fuse generation tag (t+1)&0xFF
    u32 packed = ((__float_as_uint(x_new) + 0x80u) & 0xFFFFFF00u)
               | ((u32)(t + 1) & 0xFFu);
    if ((l & 7) == 0) {
      u32* dst = pa ? d1 : d0;          // x_t -> buf[t&1]
      // PLAIN store: write-through L1 -> dirty in XCD0's shared L2
      // (r9-proven; r16 atomics and r31 sc0 both failed to beat it).
      asm volatile("global_store_dword %0, %1, off" :: "v"(dst), "v"(packed));
    }
  }
}

extern "C" void kernel_launch(void* const* d_in, const int* in_sizes, int n_in,
                              void* d_out, int out_size, void* d_ws, size_t ws_size,
                              hipStream_t stream) {
  const float* u     = (const float*)d_in[0];
  const float* w_in  = (const float*)d_in[1];
  const float* w_res = (const float*)d_in[2];
  const float* w_out = (const float*)d_in[3];
  const int*   mask  = (const int*)d_in[4];
  float* out = (float*)d_out;

  // zero the block-claim counter; packed buffers rely on 0xAA poison
  // (tag byte 0xAA only ever compared against want in {1,2})
  hipMemsetAsync(d_ws, 0, 64, stream);

  esn_kernel<<<NBLK, NT, 0, stream>>>(u, w_in, w_res, w_out, mask, out,
                                      (char*)d_ws);
}